// Round 3
// baseline (273.825 us; speedup 1.0000x reference)
//
#include <hip/hip_runtime.h>

// Masked smooth-L1 sum over 2^25 fp32 pairs -> scalar.
// R9: SINGLE-VARIABLE probe — nt -> plain loads, everything else identical
// to R8. Purpose: isolate the kernel-only rate under allocating loads.
// Evidence so far: read kernel pins at ~3.6 TB/s across 3 shapes (R6/R7/R8);
// R7 proved L3-hit reads are no faster than HBM reads (limiter is CU<->fabric
// side, shared by both) — BUT every read kernel so far used nt loads, which
// bypass L2 allocation and may route through a narrower streaming/miss path.
// Plain-load kernel-only speed was never measured (R5 conflated it with
// reset-op L3-pollution costs).
// Predicted outcomes:
//   B1 return-path cap:  partial 74-80 us, reset +15-25 us, total 260-275
//       -> declare roofline on R8 next round.
//   B2 nt-is-the-brake:  partial 45-60 us, reset +10-25 us, total 235-255
//       -> next round: inline-asm cache bits (L2-allocate, L3-bypass).

typedef float v4f __attribute__((ext_vector_type(4)));

#define BLOCK 1024
#define ITERS 4
#define CHUNK (BLOCK * ITERS)    // 4096 float4 per block per array
#define NWAVES (BLOCK / 64)      // 16

__device__ __forceinline__ float sl1_masked(float o, float t) {
    float d = fabsf(o - t);
    float s = (d < 1.0f) ? (0.5f * d * d) : (d - 0.5f);
    return (t != 0.0f) ? s : 0.0f;
}

__device__ __forceinline__ float sl1_v4(v4f o, v4f t) {
    return sl1_masked(o.x, t.x) + sl1_masked(o.y, t.y) +
           sl1_masked(o.z, t.z) + sl1_masked(o.w, t.w);
}

__global__ __launch_bounds__(BLOCK) void sl1_partial_kernel(
    const v4f* __restrict__ o4,
    const v4f* __restrict__ t4,
    float* __restrict__ partials,
    long long n4)
{
    const long long base = (long long)blockIdx.x * CHUNK + threadIdx.x;
    float acc = 0.0f;

    if (base + (ITERS - 1) * BLOCK < n4) {
        // Fast path: issue all 8 PLAIN loads up front, then consume.
        v4f o[ITERS], t[ITERS];
        #pragma unroll
        for (int k = 0; k < ITERS; ++k) {
            o[k] = o4[base + k * BLOCK];
            t[k] = t4[base + k * BLOCK];
        }
        #pragma unroll
        for (int k = 0; k < ITERS; ++k)
            acc += sl1_v4(o[k], t[k]);
    } else {
        #pragma unroll
        for (int k = 0; k < ITERS; ++k) {
            long long idx = base + (long long)k * BLOCK;
            if (idx < n4) {
                v4f o = o4[idx];
                v4f t = t4[idx];
                acc += sl1_v4(o, t);
            }
        }
    }

    // Block reduction: wave shuffle-reduce, then serial sum of 16 wave
    // partials in fixed order (deterministic, bitwise-stable).
    #pragma unroll
    for (int off = 32; off > 0; off >>= 1)
        acc += __shfl_down(acc, off, 64);
    __shared__ float wave_sums[NWAVES];
    const int lane = threadIdx.x & 63;
    const int wave = threadIdx.x >> 6;
    if (lane == 0) wave_sums[wave] = acc;
    __syncthreads();
    if (threadIdx.x == 0) {
        float s = 0.0f;
        #pragma unroll
        for (int w = 0; w < NWAVES; ++w) s += wave_sums[w];
        partials[blockIdx.x] = s;
    }
}

__global__ __launch_bounds__(256) void sl1_final_kernel(
    const float* __restrict__ partials,
    float* __restrict__ result,
    int n)
{
    float acc = 0.0f;
    for (int i = threadIdx.x; i < n; i += 256)
        acc += partials[i];
    #pragma unroll
    for (int off = 32; off > 0; off >>= 1)
        acc += __shfl_down(acc, off, 64);
    __shared__ float wave_sums[4];
    const int lane = threadIdx.x & 63;
    const int wave = threadIdx.x >> 6;
    if (lane == 0) wave_sums[wave] = acc;
    __syncthreads();
    if (threadIdx.x == 0)
        result[0] = wave_sums[0] + wave_sums[1] + wave_sums[2] + wave_sums[3];
}

extern "C" void kernel_launch(void* const* d_in, const int* in_sizes, int n_in,
                              void* d_out, int out_size, void* d_ws, size_t ws_size,
                              hipStream_t stream) {
    const v4f* o4 = (const v4f*)d_in[0];
    const v4f* t4 = (const v4f*)d_in[1];
    float* res      = (float*)d_out;
    float* partials = (float*)d_ws;

    const long long n  = (long long)in_sizes[0];  // 2^25
    const long long n4 = n / 4;                   // 8388608 = 2048 * 4096

    const int grid = (int)((n4 + CHUNK - 1) / CHUNK);  // 2048
    sl1_partial_kernel<<<grid, BLOCK, 0, stream>>>(o4, t4, partials, n4);
    sl1_final_kernel<<<1, 256, 0, stream>>>(partials, res, grid);
}

// Round 4
// 273.474 us; speedup vs baseline: 1.0013x; 1.0013x over previous
//
#include <hip/hip_runtime.h>

// Masked smooth-L1 sum over 2^25 fp32 pairs -> scalar.
// R10: CALIBRATION PROBE — faithful BabelStream-dot structure.
// Evidence: read path pins at ~3.5 TB/s for nt+chunked+dwordx4 (R6/R8),
// 2.4 TB/s for plain+chunked+dwordx4 (R9); one array is always L3-resident
// (FETCH=134 MB) and L3 hits don't help (R7) -> CU<->fabric read-path limit
// for the CHUNKED-x4 access class. BabelStream dot on MI300X reaches ~94%
// of HBM peak with a structure we never tested: PLAIN SCALAR dword loads,
// GRID-STRIDE loop, ~2 blocks/CU. This round ports that structure verbatim
// with the SL1 math fused (VALU was 9%, math is free).
// Predicted: structure-wins -> partial 38-55 us, total 215-240;
//            cap-is-real   -> partial >=90 us, total >=255, then revert to
//            R8 and declare roofline (calibrated).

#define BLOCK 1024
#define GRID  512                // 2 blocks/CU on 256 CUs
#define NWAVES (BLOCK / 64)      // 16

__global__ __launch_bounds__(BLOCK) void sl1_partial_kernel(
    const float* __restrict__ o,
    const float* __restrict__ t,
    float* __restrict__ partials,
    int n)
{
    const int stride = GRID * BLOCK;           // 524288 threads
    float acc = 0.0f;
    for (int i = blockIdx.x * BLOCK + threadIdx.x; i < n; i += stride) {
        float ov = o[i];
        float tv = t[i];
        float d  = fabsf(ov - tv);
        float s  = (d < 1.0f) ? (0.5f * d * d) : (d - 0.5f);
        acc     += (tv != 0.0f) ? s : 0.0f;
    }

    // Wave shuffle-reduce, then serial sum of 16 wave partials (fixed order).
    #pragma unroll
    for (int off = 32; off > 0; off >>= 1)
        acc += __shfl_down(acc, off, 64);
    __shared__ float wave_sums[NWAVES];
    const int lane = threadIdx.x & 63;
    const int wave = threadIdx.x >> 6;
    if (lane == 0) wave_sums[wave] = acc;
    __syncthreads();
    if (threadIdx.x == 0) {
        float s = 0.0f;
        #pragma unroll
        for (int w = 0; w < NWAVES; ++w) s += wave_sums[w];
        partials[blockIdx.x] = s;
    }
}

__global__ __launch_bounds__(256) void sl1_final_kernel(
    const float* __restrict__ partials,
    float* __restrict__ result,
    int n)
{
    float acc = 0.0f;
    for (int i = threadIdx.x; i < n; i += 256)
        acc += partials[i];
    #pragma unroll
    for (int off = 32; off > 0; off >>= 1)
        acc += __shfl_down(acc, off, 64);
    __shared__ float wave_sums[4];
    const int lane = threadIdx.x & 63;
    const int wave = threadIdx.x >> 6;
    if (lane == 0) wave_sums[wave] = acc;
    __syncthreads();
    if (threadIdx.x == 0)
        result[0] = wave_sums[0] + wave_sums[1] + wave_sums[2] + wave_sums[3];
}

extern "C" void kernel_launch(void* const* d_in, const int* in_sizes, int n_in,
                              void* d_out, int out_size, void* d_ws, size_t ws_size,
                              hipStream_t stream) {
    const float* o = (const float*)d_in[0];
    const float* t = (const float*)d_in[1];
    float* res      = (float*)d_out;
    float* partials = (float*)d_ws;

    const int n = in_sizes[0];   // 2^25

    sl1_partial_kernel<<<GRID, BLOCK, 0, stream>>>(o, t, partials, n);
    sl1_final_kernel<<<1, 256, 0, stream>>>(partials, res, GRID);
}